// Round 7
// baseline (61.334 us; speedup 1.0000x reference)
//
#include <hip/hip_runtime.h>

// Conv2D 3x3 VALID NHWC, B=16 H=W=224 C=32 F=32 -> [16,222,222,32] fp32.
// im2col GEMM M=788544 K=288 N=32, bf16 MFMA 16x16x32 (swapped: D[filt][pix]).
// Round 7: R6 still latency/LDS-bound (MfmaUtil 8.3%, LDS-read ~42k cyc/CU
// from fp32 fragments re-read 9x, VALU ~34k from per-tap perms).
//  (1) one-pass in-LDS fp32->bf16 convert to a dedicated bf16 buffer
//      (80B/pixel stride -> conflict-free b128 tap reads). Compute reads
//      1 b128/lane/tap (was 2) and per-tap perms vanish.
//  (2) exact prefetch accounting: uniform 7 loads/wave, STAGE(t+2) issued
//      after stores -> vmcnt(11) = {4 stores + 7 next loads} window keeps
//      the whole prefetch in flight (R6 drained most of it every tile).

#define HO 222
#define WO 222
#define HIN 224
#define WIN 224
#define CIN 32
#define FOUT 32

#define TH 4                      // output rows per tile
#define TW 64                     // output cols per tile
#define IR (TH + 2)               // 6 staged rows
#define IC (TW + 2)               // 66 staged cols
#define NT 7                      // tiles per block
#define PIXB 128                  // bytes per staged fp32 pixel
#define BPIXB 80                  // bytes per bf16 pixel (64B + 16B pad: 8-bank cycle)
#define STAGE_GR (IR * IC * 8)    // 3168 16B granules per fp32 tile
#define BUF_GR (STAGE_GR + 96)    // slack: overflow waves' dests land here
#define NSTG 7                    // uniform: EVERY wave issues 7 gload_lds
#define CVT_ITEMS (IR * IC * 4)   // 1584 bf16 granules per tile
#define NCVT 4

typedef __attribute__((ext_vector_type(8))) short short8;
typedef __attribute__((ext_vector_type(4))) float float4v;

__device__ inline short f2bf(float f) {                  // RNE (weights only)
    unsigned u = __builtin_bit_cast(unsigned, f);
    unsigned r = (u + 0x7FFFu + ((u >> 16) & 1u)) >> 16;
    return (short)r;
}

__global__ __launch_bounds__(512, 2) void conv3x3_mfma(
    const float* __restrict__ x,     // [16,224,224,32]
    const float* __restrict__ w,     // [32][288 = (kh,kw,c)]
    const float* __restrict__ bias,  // [32]
    float* __restrict__ out)         // [16,222,222,32]
{
    __shared__ uint4 lds_raw[2][BUF_GR];        // 2 x 52224 B fp32 stage
    __shared__ uint4 lds_bf[IR * IC * 5];       // 31680 B bf16 tile

    const int wot = blockIdx.x;            // 0..3
    const int g   = blockIdx.y;            // 0..7
    const int b   = blockIdx.z;            // 0..15
    const int wo_base = wot * TW;

    const int tid  = threadIdx.x;
    const int lane = tid & 63;

    const int fcol = lane & 15;            // A row (filter) / D col (pixel)
    const int kq   = lane >> 4;            // k-slice: k = kq*8 + i

    // ---- weights -> register A-fragments ----
    short8 bfr[2][9];
#pragma unroll
    for (int h = 0; h < 2; ++h) {
        const float* wf = w + (h * 16 + fcol) * 288 + kq * 8;
#pragma unroll
        for (int s = 0; s < 9; ++s) {
            float4 lo = reinterpret_cast<const float4*>(wf + s * 32)[0];
            float4 hi = reinterpret_cast<const float4*>(wf + s * 32)[1];
            short8 v;
            v[0] = f2bf(lo.x); v[1] = f2bf(lo.y); v[2] = f2bf(lo.z); v[3] = f2bf(lo.w);
            v[4] = f2bf(hi.x); v[5] = f2bf(hi.y); v[6] = f2bf(hi.z); v[7] = f2bf(hi.w);
            bfr[h][s] = v;
        }
    }
    const float4 bias0 = reinterpret_cast<const float4*>(bias)[kq];
    const float4 bias1 = reinterpret_cast<const float4*>(bias)[4 + kq];

    // ---- async fp32 staging, source-swizzled (G21); uniform 7 loads/wave ----
    auto STAGE = [&](int bufidx, int t) {
        char* buf = reinterpret_cast<char*>(lds_raw[bufidx]);
        const int row0 = (g * NT + t) * TH;
        const int wv64 = tid & ~63;
#pragma unroll
        for (int i = 0; i < NSTG; ++i) {
            int wb = wv64 + i * 512;
            if (wb > STAGE_GR) wb = STAGE_GR;        // overflow waves -> slack
            int dgid = wb + lane;                    // dest = uniform base + lane
            int gg   = wb + lane;
            if (gg > STAGE_GR - 1) gg = STAGE_GR - 1;  // src clamp (dup, benign)
            int plin = gg >> 3;
            int sub  = (gg & 7) ^ (plin & 7);        // pre-swizzled source granule
            int row  = plin / IC;
            int col  = plin - row * IC;
            int ir  = row0 + row;    if (ir  > HIN - 1) ir  = HIN - 1;
            int icl = wo_base + col; if (icl > WIN - 1) icl = WIN - 1;
            const float* src = x + ((b * HIN + ir) * WIN + icl) * CIN + sub * 4;
            __builtin_amdgcn_global_load_lds(
                (const __attribute__((address_space(1))) void*)src,
                (__attribute__((address_space(3))) void*)(buf + dgid * 16),
                16, 0, 0);
        }
    };

    // ---- in-LDS fp32 -> bf16 convert (once per staged pixel) ----
    auto CONVERT = [&](int bufidx) {
        const char* fbuf = reinterpret_cast<const char*>(lds_raw[bufidx]);
        char* bbuf = reinterpret_cast<char*>(lds_bf);
#pragma unroll
        for (int i = 0; i < NCVT; ++i) {
            int id = tid + i * 512;
            if (id < CVT_ITEMS) {
                int p   = id >> 2;                   // pixel
                int k   = id & 3;                    // 8-ch chunk
                int key = p & 7;
                const uint4 ua = *reinterpret_cast<const uint4*>(
                    fbuf + p * PIXB + (((2 * k) ^ key) << 4));      // ch 8k..+3
                const uint4 ub = *reinterpret_cast<const uint4*>(
                    fbuf + p * PIXB + (((2 * k + 1) ^ key) << 4));  // ch 8k+4..+7
                unsigned w0 = __builtin_amdgcn_perm(ua.y, ua.x, 0x07060302u);
                unsigned w1 = __builtin_amdgcn_perm(ua.w, ua.z, 0x07060302u);
                unsigned w2 = __builtin_amdgcn_perm(ub.y, ub.x, 0x07060302u);
                unsigned w3 = __builtin_amdgcn_perm(ub.w, ub.z, 0x07060302u);
                uint4 pk = {w0, w1, w2, w3};
                *reinterpret_cast<uint4*>(bbuf + p * BPIXB + k * 16) = pk;
            }
        }
    };

    // ---------- prologue: 2 tiles in flight ----------
    STAGE(0, 0);
    STAGE(1, 1);

    const char* bbuf = reinterpret_cast<const char*>(lds_bf);

#pragma unroll 1
    for (int t = 0; t < NT; ++t) {
        // retire tile-t loads; younger window = {4 stores(t-1), 7 loads(t+1)}
        if (t == 0)          asm volatile("s_waitcnt vmcnt(7)" ::: "memory");
        else if (t < NT - 1) asm volatile("s_waitcnt vmcnt(11)" ::: "memory");
        else                 asm volatile("s_waitcnt vmcnt(4)" ::: "memory");
        __builtin_amdgcn_sched_barrier(0);
        __builtin_amdgcn_s_barrier();
        __builtin_amdgcn_sched_barrier(0);

        CONVERT(t & 1);

        asm volatile("s_waitcnt lgkmcnt(0)" ::: "memory");
        __builtin_amdgcn_sched_barrier(0);
        __builtin_amdgcn_s_barrier();
        __builtin_amdgcn_sched_barrier(0);

        const int row0 = (g * NT + t) * TH;
        const int wave = tid >> 6;

#pragma unroll
        for (int j = 0; j < 2; ++j) {
            const int chunk = wave * 2 + j;              // 16 chunks of 16 pixels
            const int pix = chunk * 16 + fcol;
            const int hoo = pix >> 6;
            const int woo = pix & 63;

            float4v acc0 = {0.f, 0.f, 0.f, 0.f};
            float4v acc1 = {0.f, 0.f, 0.f, 0.f};
#pragma unroll
            for (int s = 0; s < 9; ++s) {
                const int kh = s / 3, kw = s % 3;
                const int plin = (hoo + kh) * IC + (woo + kw);
                const short8 a = *reinterpret_cast<const short8*>(
                    bbuf + plin * BPIXB + kq * 16);      // 8 bf16 ch, 1 b128
                acc0 = __builtin_amdgcn_mfma_f32_16x16x32_bf16(bfr[0][s], a, acc0, 0, 0, 0);
                acc1 = __builtin_amdgcn_mfma_f32_16x16x32_bf16(bfr[1][s], a, acc1, 0, 0, 0);
            }

            const int ho = row0 + hoo;
            const int wo = wo_base + woo;
            if (ho < HO && wo < WO) {
                float* o = out + ((b * HO + ho) * WO + wo) * FOUT;
                float4 v0 = {acc0[0] + bias0.x, acc0[1] + bias0.y,
                             acc0[2] + bias0.z, acc0[3] + bias0.w};
                float4 v1 = {acc1[0] + bias1.x, acc1[1] + bias1.y,
                             acc1[2] + bias1.z, acc1[3] + bias1.w};
                reinterpret_cast<float4*>(o)[kq]     = v0;
                reinterpret_cast<float4*>(o)[4 + kq] = v1;
            }
        }

        if (t + 2 < NT) STAGE(t & 1, t + 2);   // after stores: exact vmcnt window
    }
}

extern "C" void kernel_launch(void* const* d_in, const int* in_sizes, int n_in,
                              void* d_out, int out_size, void* d_ws, size_t ws_size,
                              hipStream_t stream) {
    const float* x    = (const float*)d_in[0];
    const float* w    = (const float*)d_in[1];
    const float* bias = (const float*)d_in[2];
    float* out        = (float*)d_out;

    dim3 grid(4, 8, 16);    // wot, row-group (7 tiles of 4 rows), batch
    dim3 block(512);
    conv3x3_mfma<<<grid, block, 0, stream>>>(x, w, bias, out);
}

// Round 8
// 49.675 us; speedup vs baseline: 1.2347x; 1.2347x over previous
//
#include <hip/hip_runtime.h>

// Conv2D 3x3 VALID NHWC, B=16 H=W=224 C=32 F=32 -> [16,222,222,32] fp32.
// im2col GEMM M=788544 K=288 N=32, bf16 MFMA 16x16x32 (swapped: D[filt][pix]).
// Round 8: ring-buffer restructure. R7 analysis: 14k cyc/tile vs 8.2k fabric
// floor, floor itself inflated 1.55x by vertical halo re-staging.
//  - 16-row fp32 ring (slot = row & 15): stage only 4 NEW rows per tile
//    (33.8 KB vs 50.7) -> per-tile fabric 66.6 KB = 6.5k cyc floor.
//  - grid = 256 blocks exactly (1/CU, 14 tiles each, no 2nd block round).
//  - uniform 5 gload_lds/wave/chunk (rows padded to 9216 B so wave segments
//    never straddle rows; overflow waves -> slack). Depth-3 chunks in
//    flight; waits are pure-load windows vmcnt(10) -- stores are always
//    OLDER than the window so guarded-store count can't break accounting.
//  - convert-on-read perms (R7 proved separate convert phase is a loss).

#define HO 222
#define WO 222
#define HIN 224
#define WIN 224
#define CIN 32
#define FOUT 32

#define TW 64                  // output cols per block
#define IC 66                  // staged cols (64 + 2 halo)
#define TH 4                   // output rows per tile
#define NT 14                  // tiles per block
#define GROWS 56               // output rows per block
#define NCHUNK 15              // 4-row stage chunks (rows 0..59 rel)
#define RB 16                  // ring rows (power of 2 -> slot = row & 15)
#define ROWB 9216              // padded row bytes: 576 granules (528 data)
#define SLACKB 1024            // dump area for overflow stage waves

typedef __attribute__((ext_vector_type(8))) short short8;
typedef __attribute__((ext_vector_type(4))) float float4v;

__device__ inline short f2bf(float f) {                  // RNE (weights only)
    unsigned u = __builtin_bit_cast(unsigned, f);
    unsigned r = (u + 0x7FFFu + ((u >> 16) & 1u)) >> 16;
    return (short)r;
}

__global__ __launch_bounds__(512, 2) void conv3x3_mfma(
    const float* __restrict__ x,     // [16,224,224,32]
    const float* __restrict__ w,     // [32][288 = (kh,kw,c)]
    const float* __restrict__ bias,  // [32]
    float* __restrict__ out)         // [16,222,222,32]
{
    __shared__ uint4 lds_raw[(RB * ROWB + SLACKB) / 16];   // 148480 B
    char* ldsc  = reinterpret_cast<char*>(lds_raw);
    char* slack = ldsc + RB * ROWB;

    const int wot = blockIdx.x;            // 0..3
    const int g   = blockIdx.y;            // 0..3 row groups
    const int b   = blockIdx.z;            // 0..15
    const int wo_base = wot * TW;
    const int gr0 = g * GROWS;

    const int tid  = threadIdx.x;
    const int lane = tid & 63;
    const int wave = tid >> 6;             // 0..7

    const int fcol = lane & 15;            // A row (filter) / D col (pixel)
    const int kq   = lane >> 4;            // k-slice: k = kq*8 + i

    // ---- weights -> register A-fragments (older than all stage loads;
    //      drained by the first vmcnt window) ----
    short8 bfr[2][9];
#pragma unroll
    for (int h = 0; h < 2; ++h) {
        const float* wf = w + (h * 16 + fcol) * 288 + kq * 8;
#pragma unroll
        for (int s = 0; s < 9; ++s) {
            float4 lo = reinterpret_cast<const float4*>(wf + s * 32)[0];
            float4 hi = reinterpret_cast<const float4*>(wf + s * 32)[1];
            short8 v;
            v[0] = f2bf(lo.x); v[1] = f2bf(lo.y); v[2] = f2bf(lo.z); v[3] = f2bf(lo.w);
            v[4] = f2bf(hi.x); v[5] = f2bf(hi.y); v[6] = f2bf(hi.z); v[7] = f2bf(hi.w);
            bfr[h][s] = v;
        }
    }
    const float4 bias0 = reinterpret_cast<const float4*>(bias)[kq];
    const float4 bias1 = reinterpret_cast<const float4*>(bias)[4 + kq];

    // ---- stage chunk k = input rows gr0+4k .. gr0+4k+3 into ring slots
    //      (4k..4k+3)&15. Waves 2j,2j+1 own row j; segs of 64 granules;
    //      seg 9 (odd waves, i=4) -> slack; seg 8 tail lands in row pad. ----
    auto STAGE = [&](int k) {
        const int j    = wave >> 1;
        const int half = wave & 1;
        int ir = gr0 + 4 * k + j; if (ir > HIN - 1) ir = HIN - 1;
        const int slot = (4 * k + j) & (RB - 1);
        char* rowbase = ldsc + slot * ROWB;
#pragma unroll
        for (int i = 0; i < 5; ++i) {
            const int seg  = half + 2 * i;           // 0..9, uniform per wave
            const int gidr = seg * 64 + lane;        // granule within row
            int c = gidr >> 3; if (c > IC - 1) c = IC - 1;
            const int gsub = (gidr & 7) ^ (c & 7);   // pre-swizzled source granule
            int icl = wo_base + c; if (icl > WIN - 1) icl = WIN - 1;
            const float* src = x + ((b * HIN + ir) * WIN + icl) * CIN + gsub * 4;
            char* dst = (seg < 9 ? rowbase + seg * 1024 : slack) + lane * 16;
            __builtin_amdgcn_global_load_lds(
                (const __attribute__((address_space(1))) void*)src,
                (__attribute__((address_space(3))) void*)dst,
                16, 0, 0);
        }
    };

    // ---------- prologue: 3 chunks in flight ----------
    STAGE(0); STAGE(1); STAGE(2);

#pragma unroll 1
    for (int t = 0; t < NT; ++t) {
        if (t + 3 < NCHUNK) STAGE(t + 3);

        // retire chunks <= t+1 (compute needs rows 4t..4t+5 = chunks t,t+1);
        // keep the 2 prefetch chunks (5 loads/wave each) in flight.
        if (t + 3 < NCHUNK)      asm volatile("s_waitcnt vmcnt(10)" ::: "memory");
        else if (t + 2 < NCHUNK) asm volatile("s_waitcnt vmcnt(5)" ::: "memory");
        else                     asm volatile("s_waitcnt vmcnt(0)" ::: "memory");
        __builtin_amdgcn_sched_barrier(0);
        __builtin_amdgcn_s_barrier();
        __builtin_amdgcn_sched_barrier(0);

        const int rbase = 4 * t;               // tile's first input row (rel)

#pragma unroll
        for (int j = 0; j < 2; ++j) {
            const int chunk = wave * 2 + j;    // 16 chunks of 16 pixels
            const int pix = chunk * 16 + fcol;
            const int hoo = pix >> 6;          // 0..3
            const int woo = pix & 63;

            float4v acc0 = {0.f, 0.f, 0.f, 0.f};
            float4v acc1 = {0.f, 0.f, 0.f, 0.f};
#pragma unroll
            for (int s = 0; s < 9; ++s) {
                const int kh = s / 3, kw = s % 3;
                const int slot = (rbase + hoo + kh) & (RB - 1);
                const int c  = woo + kw;
                const int g0 = (2 * kq) ^ (c & 7);
                const char* px = ldsc + slot * ROWB + c * 128;
                const uint4 ua = *reinterpret_cast<const uint4*>(px + g0 * 16);
                const uint4 ub = *reinterpret_cast<const uint4*>(px + (g0 ^ 1) * 16);
                // ua: source granule g0^key = 2kq  -> channels 8kq..+3
                // ub: source granule 2kq+1        -> channels 8kq+4..+7
                unsigned w0 = __builtin_amdgcn_perm(ua.y, ua.x, 0x07060302u);
                unsigned w1 = __builtin_amdgcn_perm(ua.w, ua.z, 0x07060302u);
                unsigned w2 = __builtin_amdgcn_perm(ub.y, ub.x, 0x07060302u);
                unsigned w3 = __builtin_amdgcn_perm(ub.w, ub.z, 0x07060302u);
                uint4 packed = {w0, w1, w2, w3};
                short8 a = __builtin_bit_cast(short8, packed);
                acc0 = __builtin_amdgcn_mfma_f32_16x16x32_bf16(bfr[0][s], a, acc0, 0, 0, 0);
                acc1 = __builtin_amdgcn_mfma_f32_16x16x32_bf16(bfr[1][s], a, acc1, 0, 0, 0);
            }

            // D[filter][pixel]: col(lane&15)=pixel, row=kq*4+r=filter
            const int ho = gr0 + rbase + hoo;
            const int wo = wo_base + woo;
            if (ho < HO && wo < WO) {
                float* o = out + ((b * HO + ho) * WO + wo) * FOUT;
                float4 v0 = {acc0[0] + bias0.x, acc0[1] + bias0.y,
                             acc0[2] + bias0.z, acc0[3] + bias0.w};
                float4 v1 = {acc1[0] + bias1.x, acc1[1] + bias1.y,
                             acc1[2] + bias1.z, acc1[3] + bias1.w};
                reinterpret_cast<float4*>(o)[kq]     = v0;
                reinterpret_cast<float4*>(o)[4 + kq] = v1;
            }
        }

        // all waves done reading tile t's slots before next STAGE overwrites
        // slots (4t+12..15)&15 (= rows 4t-4..4t-1 of the ring).
        __builtin_amdgcn_sched_barrier(0);
        __builtin_amdgcn_s_barrier();
        __builtin_amdgcn_sched_barrier(0);
    }
}

extern "C" void kernel_launch(void* const* d_in, const int* in_sizes, int n_in,
                              void* d_out, int out_size, void* d_ws, size_t ws_size,
                              hipStream_t stream) {
    const float* x    = (const float*)d_in[0];
    const float* w    = (const float*)d_in[1];
    const float* bias = (const float*)d_in[2];
    float* out        = (float*)d_out;

    dim3 grid(4, 4, 16);    // col-tile, row-group (56 rows), batch = 256 blocks
    dim3 block(512);
    conv3x3_mfma<<<grid, block, 0, stream>>>(x, w, bias, out);
}